// Round 8
// baseline (572.685 us; speedup 1.0000x reference)
//
#include <hip/hip_runtime.h>
#include <hip/hip_bf16.h>

// GAT on two 512-node cliques + bipartite cross edges, 5 GATConv layers.
// Dense-in-disguise edges: "inside" = clique within each set (+self),
// "cross" = full bipartite to opposite set (+self).
//
// R8: SINGLE persistent kernel (256 blocks x 512 threads, 1 block/CU,
// co-residency proven R5) with a LOAD-ONLY spin barrier replacing R5's
// RMW-contended one (R5: ~49us/barrier from 256 blocks hammering one line
// with atomicAdd; fix: per-block arrival flag stores + block-0 fan-in poll
// + single release word polled with relaxed atomic LOADS + s_sleep backoff).
// Phase bodies are verbatim validated code: R6 layer (absmax 0), R5 mega
// mm2/attF (absmax 0). Magic sentinel != 0xAA poison => no init dispatch.
// All internal f32; input/output dtype runtime-detected f32/bf16.

typedef __hip_bfloat16 bf16;

#define MAGIC 0x13579BDFu

__device__ __forceinline__ float b2f(bf16 x) { return __bfloat162float(x); }

__device__ __forceinline__ int detect_bf16(const void* desc1) {
  const unsigned* u = (const unsigned*)desc1;
  int hits = 0;
#pragma unroll 8
  for (int i = 0; i < 256; ++i) {
    unsigned e = (u[i] >> 7) & 0xFFu;
    hits += (e >= 100u && e <= 140u) ? 1 : 0;
  }
  return hits >= 200 ? 1 : 0;
}

__device__ __forceinline__ float load_in(const void* p, int i, int bf) {
  return bf ? b2f(((const bf16*)p)[i]) : ((const float*)p)[i];
}

// Load-only grid barrier.  flags: 256 words (this phase), rel: 1 word.
// ws is poisoned 0xAA before every launch, so MAGIC-sentinel needs no init.
__device__ __forceinline__ void gbar(unsigned* __restrict__ flags,
                                     unsigned* __restrict__ rel,
                                     int b, int tid) {
  __syncthreads();
  __threadfence();  // release: my phase writes visible device-wide
  if (b == 0) {
    if (tid > 0 && tid < 256) {  // fan-in: each thread polls one block's flag
      while (__hip_atomic_load(flags + tid, __ATOMIC_RELAXED,
                               __HIP_MEMORY_SCOPE_AGENT) != MAGIC)
        __builtin_amdgcn_s_sleep(8);
    }
    __syncthreads();
    if (tid == 0)
      __hip_atomic_store(rel, MAGIC, __ATOMIC_RELEASE,
                         __HIP_MEMORY_SCOPE_AGENT);
  } else {
    if (tid == 0) {
      __hip_atomic_store(flags + b, MAGIC, __ATOMIC_RELEASE,
                         __HIP_MEMORY_SCOPE_AGENT);
      while (__hip_atomic_load(rel, __ATOMIC_RELAXED,
                               __HIP_MEMORY_SCOPE_AGENT) != MAGIC)
        __builtin_amdgcn_s_sleep(8);
    }
  }
  __syncthreads();
  __threadfence();  // acquire: other blocks' writes visible to me
}

// ---------------------------------------------------------- layer phase ----
// Block (hd,S): sources = set S; dst = S (inside) or 1-S (cross).
// Direct dense softmax, float4 LDS broadcasts, 4 acc chains (R6, absmax 0).
__device__ __forceinline__ void layer_phase(
    int cross, int hd, int S, int tid,
    const float* __restrict__ xt_in, float* __restrict__ xt_out,
    const float* __restrict__ Wf, const float* __restrict__ vecs,
    float* sm) {
  float* ssA = sm;        // 512
  float* hhA = sm + 512;  // 512

  const int D = cross ? (1 - S) : S;
  const float a_src = vecs[hd], a_dst = vecs[128 + hd], bias = vecs[256 + hd];

  // Phase A: h column for this head (src set; dst set too if cross).
  float accSa = 0.f, accSb = 0.f, accDa = 0.f, accDb = 0.f;
#pragma unroll 8
  for (int k = 0; k < 128; k += 2) {
    float w0 = Wf[k * 128 + hd];
    float w1 = Wf[(k + 1) * 128 + hd];
    accSa = fmaf(xt_in[k * 1024 + S * 512 + tid],       w0, accSa);
    accSb = fmaf(xt_in[(k + 1) * 1024 + S * 512 + tid], w1, accSb);
    if (cross) {
      accDa = fmaf(xt_in[k * 1024 + D * 512 + tid],       w0, accDa);
      accDb = fmaf(xt_in[(k + 1) * 1024 + D * 512 + tid], w1, accDb);
    }
  }
  const float h_src = accSa + accSb;
  const float h_dst = cross ? (accDa + accDb) : h_src;
  const float d_own = h_dst * a_dst;
  ssA[tid] = h_src * a_src;
  hhA[tid] = h_src;
  __syncthreads();

  // Phase B: direct reduction, 4 src per float4 broadcast, 4 acc chains.
  float den0 = 0.f, den1 = 0.f, den2 = 0.f, den3 = 0.f;
  float num0 = 0.f, num1 = 0.f, num2 = 0.f, num3 = 0.f;
#pragma unroll 4
  for (int j = 0; j < 512; j += 4) {
    float4 sv = *(const float4*)(ssA + j);
    float4 hv = *(const float4*)(hhA + j);
    float t0 = sv.x + d_own, t1 = sv.y + d_own;
    float t2 = sv.z + d_own, t3 = sv.w + d_own;
    float p0 = __expf(fmaxf(t0, 0.2f * t0));
    float p1 = __expf(fmaxf(t1, 0.2f * t1));
    float p2 = __expf(fmaxf(t2, 0.2f * t2));
    float p3 = __expf(fmaxf(t3, 0.2f * t3));
    den0 += p0; num0 = fmaf(p0, hv.x, num0);
    den1 += p1; num1 = fmaf(p1, hv.y, num1);
    den2 += p2; num2 = fmaf(p2, hv.z, num2);
    den3 += p3; num3 = fmaf(p3, hv.w, num3);
  }
  float den = (den0 + den1) + (den2 + den3);
  float num = (num0 + num1) + (num2 + num3);
  if (cross) {  // self-loop: dst node's own source score
    float t = h_dst * a_src + d_own;
    float p = __expf(fmaxf(t, 0.2f * t));
    den += p;
    num = fmaf(p, h_dst, num);
  }
  float o = num / (den + 1e-16f) + bias;
  o = (o > 0.f) ? o : expm1f(o);  // ELU
  xt_out[hd * 1024 + D * 512 + tid] = o;
}

// ------------------------------------------------------------ mega kernel ----
__global__ __launch_bounds__(512) void mega_kernel(
    const void* __restrict__ desc1, const void* __restrict__ desc2,
    const void* __restrict__ W1,   const void* __restrict__ as1,
    const void* __restrict__ ad1,  const void* __restrict__ b1,
    const void* __restrict__ W2,   const void* __restrict__ as2,
    const void* __restrict__ ad2,  const void* __restrict__ b2_,
    float* __restrict__ xtA, float* __restrict__ xtB,
    float* __restrict__ h2,  float* __restrict__ W1f,
    float* __restrict__ W2f, float* __restrict__ vecs,
    float* __restrict__ s2,  float* __restrict__ d2,
    unsigned* __restrict__ bar, void* __restrict__ out) {
  __shared__ float sm[2048];  // 8 KB, reused across phases
  const int tid = threadIdx.x;
  const int b   = blockIdx.x;
  const int hd  = b & 127;
  const int S   = b >> 7;
  const int bf  = detect_bf16(desc1);

  // bar layout: 6 phases x (256 flags); then 6 release words spaced 32 apart.
  unsigned* rel = bar + 6 * 256;

  // ---- P0: prep (convert inputs to f32, transpose x) ----
  {
    const int total = 131072 + 16384 + 16384 + 6 * 128;
    for (int idx = b * 512 + tid; idx < total; idx += 131072) {
      if (idx < 131072) {
        int n = idx & 1023, c = idx >> 10;
        float v = (n < 512) ? load_in(desc1, n * 128 + c, bf)
                            : load_in(desc2, (n - 512) * 128 + c, bf);
        xtA[idx] = v;  // xt[c*1024 + n]
      } else if (idx < 147456) {
        W1f[idx - 131072] = load_in(W1, idx - 131072, bf);
      } else if (idx < 163840) {
        W2f[idx - 147456] = load_in(W2, idx - 147456, bf);
      } else {
        int i = idx - 163840, o = i & 127;
        float v;
        if      (i < 128) v = load_in(as1, o, bf);
        else if (i < 256) v = load_in(ad1, o, bf);
        else if (i < 384) v = load_in(b1, o, bf);
        else if (i < 512) v = load_in(as2, o, bf);
        else if (i < 640) v = load_in(ad2, o, bf);
        else              v = load_in(b2_, o, bf);
        vecs[i] = v;
      }
    }
  }
  gbar(bar + 0 * 256, rel + 0 * 32, b, tid);

  // ---- P1..P4: four GAT layers (R6 body) ----
  layer_phase(0, hd, S, tid, xtA, xtB, W1f, vecs, sm);
  gbar(bar + 1 * 256, rel + 1 * 32, b, tid);
  layer_phase(1, hd, S, tid, xtB, xtA, W1f, vecs, sm);
  gbar(bar + 2 * 256, rel + 2 * 32, b, tid);
  layer_phase(0, hd, S, tid, xtA, xtB, W1f, vecs, sm);
  gbar(bar + 3 * 256, rel + 3 * 32, b, tid);
  layer_phase(1, hd, S, tid, xtB, xtA, W1f, vecs, sm);
  gbar(bar + 4 * 256, rel + 4 * 32, b, tid);

  // ---- P5: mm2 (h2 = x@W2, s2/d2 row dots).  4 rows x 128 cols/block ----
  {
    float* rs = sm;        // 512
    float* rd = sm + 512;  // 512
    const int row = b * 4 + (tid >> 7);
    const int c = tid & 127;
    float acca = 0.f, accb = 0.f;
#pragma unroll 8
    for (int k = 0; k < 128; k += 2) {
      acca = fmaf(xtA[k * 1024 + row], W2f[k * 128 + c], acca);
      accb = fmaf(xtA[(k + 1) * 1024 + row], W2f[(k + 1) * 128 + c], accb);
    }
    float acc = acca + accb;
    h2[row * 128 + c] = acc;
    rs[tid] = acc * vecs[384 + c];  // a_src2
    rd[tid] = acc * vecs[512 + c];  // a_dst2
    __syncthreads();
    for (int off = 64; off > 0; off >>= 1) {
      if ((tid & 127) < off) { rs[tid] += rs[tid + off]; rd[tid] += rd[tid + off]; }
      __syncthreads();
    }
    if ((tid & 127) == 0) {
      s2[row] = rs[tid];
      d2[row] = rd[tid];
    }
    __syncthreads();
  }
  gbar(bar + 5 * 256, rel + 5 * 32, b, tid);

  // ---- P6: final attention (heads=1, ch=128), direct weighted row-sum ----
  {
    float* pL = sm;  // [4][512]
    const int dstBase = b * 4;
    const int srcBase = (dstBase < 512) ? 512 : 0;  // cross edges

    for (int e = tid; e < 2048; e += 512) {
      int ld = e >> 9, j = e & 511;
      float t = s2[srcBase + j] + d2[dstBase + ld];
      pL[ld * 512 + j] = __expf(fmaxf(t, 0.2f * t));
    }
    __syncthreads();

    const int ld = tid >> 7, c = tid & 127;
    const int i = dstBase + ld;
    float acc = 0.f, den = 0.f;
    const float* hrow = h2 + srcBase * 128 + c;
#pragma unroll 4
    for (int j = 0; j < 512; ++j) {
      float p = pL[ld * 512 + j];
      den += p;
      acc = fmaf(p, hrow[j * 128], acc);
    }
    float ts = s2[i] + d2[i];
    float ps = __expf(fmaxf(ts, 0.2f * ts));  // self-loop
    den += ps;
    acc = fmaf(ps, h2[i * 128 + c], acc);
    float o = acc / (den + 1e-16f) + vecs[640 + c];
    if (bf) ((bf16*)out)[i * 128 + c] = __float2bfloat16(o);
    else    ((float*)out)[i * 128 + c] = o;
  }
}

// ------------------------------------------------------------- launcher ----
extern "C" void kernel_launch(void* const* d_in, const int* in_sizes, int n_in,
                              void* d_out, int out_size, void* d_ws, size_t ws_size,
                              hipStream_t stream) {
  (void)in_sizes; (void)n_in; (void)out_size; (void)ws_size;
  float* ws   = (float*)d_ws;
  float* xtA  = ws;            // 131072
  float* xtB  = ws + 131072;   // 131072
  float* h2   = ws + 262144;   // 131072
  float* W1f  = ws + 393216;   // 16384
  float* W2f  = ws + 409600;   // 16384
  float* vecs = ws + 425984;   // 768
  float* s2   = ws + 426752;   // 1024
  float* d2   = ws + 427776;   // 1024
  unsigned* bar = (unsigned*)(ws + 428800);  // 6*256 flags + 6*32 release

  mega_kernel<<<256, 512, 0, stream>>>(
      d_in[0], d_in[1], d_in[2], d_in[3], d_in[4], d_in[5],
      d_in[6], d_in[7], d_in[8], d_in[9],
      xtA, xtB, h2, W1f, W2f, vecs, s2, d2, bar, d_out);
}

// Round 9
// 206.213 us; speedup vs baseline: 2.7772x; 2.7772x over previous
//
#include <hip/hip_runtime.h>
#include <hip/hip_bf16.h>

// GAT on two 512-node cliques + bipartite cross edges, 5 GATConv layers.
// Dense-in-disguise edges: "inside" = clique within each set (+self),
// "cross" = full bipartite to opposite set (+self).
//
// R9: layers 1-4 use the separable softmax (R4, absmax 0):
//   exp(lrelu(s_j+d_i)) = exp(s_j)exp(d_i)      if s_j >= -d_i
//                       = exp(.2s_j)exp(.2d_i)  otherwise
// with the O(N^2) rank loop replaced by an O(N) LDS counting sort:
// monotone range-binning into 512 buckets => prefix buckets are strictly
// < theta, suffix buckets strictly >= theta, only the boundary bucket
// (avg ~1-3 elems) is compared exactly; within-bucket order is irrelevant
// to the prefix/suffix sums. Float4 Hillis-Steele scans as in R4.
// prep/mm2/att2 verbatim R6. 7 dispatches (persistent-kernel grid sync
// measured 60-75us/barrier in R5/R8 — abandoned).
// All internal f32; input/output dtype runtime-detected f32/bf16.

typedef __hip_bfloat16 bf16;

__device__ __forceinline__ float b2f(bf16 x) { return __bfloat162float(x); }

__device__ __forceinline__ int detect_bf16(const void* desc1) {
  const unsigned* u = (const unsigned*)desc1;
  int hits = 0;
#pragma unroll 8
  for (int i = 0; i < 256; ++i) {
    unsigned e = (u[i] >> 7) & 0xFFu;
    hits += (e >= 100u && e <= 140u) ? 1 : 0;
  }
  return hits >= 200 ? 1 : 0;
}

__device__ __forceinline__ float load_in(const void* p, int i, int bf) {
  return bf ? b2f(((const bf16*)p)[i]) : ((const float*)p)[i];
}

// ---------------------------------------------------------------- prep ----
__global__ __launch_bounds__(256) void prep_kernel(
    const void* __restrict__ desc1, const void* __restrict__ desc2,
    const void* __restrict__ W1,   const void* __restrict__ as1,
    const void* __restrict__ ad1,  const void* __restrict__ b1,
    const void* __restrict__ W2,   const void* __restrict__ as2,
    const void* __restrict__ ad2,  const void* __restrict__ b2,
    float* __restrict__ xt, float* __restrict__ W1f, float* __restrict__ W2f,
    float* __restrict__ vecs, int* __restrict__ flag) {
  const int bf = detect_bf16(desc1);
  if (blockIdx.x == 0 && threadIdx.x == 0) *flag = bf;
  const int total = 131072 + 16384 + 16384 + 6 * 128;
  for (int idx = blockIdx.x * blockDim.x + threadIdx.x; idx < total;
       idx += gridDim.x * blockDim.x) {
    if (idx < 131072) {
      int n = idx & 1023, c = idx >> 10;
      float v = (n < 512) ? load_in(desc1, n * 128 + c, bf)
                          : load_in(desc2, (n - 512) * 128 + c, bf);
      xt[idx] = v;  // xt[c*1024 + n]
    } else if (idx < 147456) {
      W1f[idx - 131072] = load_in(W1, idx - 131072, bf);
    } else if (idx < 163840) {
      W2f[idx - 147456] = load_in(W2, idx - 147456, bf);
    } else {
      int i = idx - 163840, o = i & 127;
      float v;
      if      (i < 128) v = load_in(as1, o, bf);
      else if (i < 256) v = load_in(ad1, o, bf);
      else if (i < 384) v = load_in(b1, o, bf);
      else if (i < 512) v = load_in(as2, o, bf);
      else if (i < 640) v = load_in(ad2, o, bf);
      else              v = load_in(b2, o, bf);
      vecs[i] = v;
    }
  }
}

// ------------------------------------------------------- fused GAT layer ----
// grid 256 = (S<<7)|hd, 512 threads.  Sources = set S; dst = S (inside) or
// 1-S (cross).  Thread tid owns src node S*512+tid AND dst node D*512+tid.
template <int CROSS>
__global__ __launch_bounds__(512) void layer_kernel(
    const float* __restrict__ xt_in, float* __restrict__ xt_out,
    const float* __restrict__ Wf, const float* __restrict__ vecs) {
  __shared__ __align__(16) float sS[512];      // bucket-ordered s
  __shared__ __align__(16) float sH[512];      // bucket-ordered h
  __shared__ unsigned hA[512];                 // hist / scan ping
  __shared__ unsigned hB[512];                 // scan pong
  __shared__ unsigned binNext[512];
  __shared__ float4 scanA[512];
  __shared__ float4 scanB[512];
  __shared__ float red[16];

  const int tid = threadIdx.x;
  const int hd  = blockIdx.x & 127;
  const int S   = blockIdx.x >> 7;
  const int D   = CROSS ? (1 - S) : S;
  const float a_src = vecs[hd], a_dst = vecs[128 + hd], bias = vecs[256 + hd];

  // Phase A: h column for this head (src set; dst set too if cross).
  float accSa = 0.f, accSb = 0.f, accDa = 0.f, accDb = 0.f;
#pragma unroll 8
  for (int k = 0; k < 128; k += 2) {
    float w0 = Wf[k * 128 + hd];
    float w1 = Wf[(k + 1) * 128 + hd];
    accSa = fmaf(xt_in[k * 1024 + S * 512 + tid],       w0, accSa);
    accSb = fmaf(xt_in[(k + 1) * 1024 + S * 512 + tid], w1, accSb);
    if (CROSS) {
      accDa = fmaf(xt_in[k * 1024 + D * 512 + tid],       w0, accDa);
      accDb = fmaf(xt_in[(k + 1) * 1024 + D * 512 + tid], w1, accDb);
    }
  }
  const float h_src = accSa + accSb;
  const float h_dst = CROSS ? (accDa + accDb) : h_src;
  const float s_own = h_src * a_src;
  const float d_own = h_dst * a_dst;

  // Phase B1: block min/max of s (wave shuffle + LDS combine).
  {
    float mn = s_own, mx = s_own;
#pragma unroll
    for (int off = 32; off > 0; off >>= 1) {
      mn = fminf(mn, __shfl_down(mn, off));
      mx = fmaxf(mx, __shfl_down(mx, off));
    }
    if ((tid & 63) == 0) { red[tid >> 6] = mn; red[8 + (tid >> 6)] = mx; }
  }
  hA[tid] = 0;        // zero hist
  binNext[tid] = 0;
  __syncthreads();
  float mn = fminf(fminf(fminf(red[0], red[1]), fminf(red[2], red[3])),
                   fminf(fminf(red[4], red[5]), fminf(red[6], red[7])));
  float mx = fmaxf(fmaxf(fmaxf(red[8], red[9]), fmaxf(red[10], red[11])),
                   fmaxf(fmaxf(red[12], red[13]), fmaxf(red[14], red[15])));
  const float scale = 512.0f / fmaxf(mx - mn, 1e-20f);

  // Phase B2: histogram.  bin(x) monotone non-decreasing.
  const int myBin = (int)fminf(fmaxf((s_own - mn) * scale, 0.0f), 511.0f);
  atomicAdd(&hA[myBin], 1u);
  __syncthreads();

  // Phase B3: inclusive scan of hist (9 steps, ping-pong hA<->hB).
  {
    unsigned* a = hA;
    unsigned* c = hB;
    for (int d = 1; d < 512; d <<= 1) {
      unsigned v = a[tid];
      if (tid >= d) v += a[tid - d];
      c[tid] = v;
      __syncthreads();
      unsigned* t = a; a = c; c = t;
    }
  }
  // after 9 swaps the inclusive scan IS lives in hB (odd #iterations).
  const unsigned* IS = hB;

  // Phase B4: scatter into bucket-ordered arrays (order within bucket free).
  {
    unsigned base = myBin ? IS[myBin - 1] : 0u;
    unsigned pos = base + atomicAdd(&binNext[myBin], 1u);
    sS[pos] = s_own;
    sH[pos] = h_src;
  }
  __syncthreads();

  // Phase B5: exp + pack (E2, E2*h, rev(E1), rev(E1*h))  [R4, absmax 0].
  {
    float sv = sS[tid];
    float hv = sH[tid];
    float e1 = __expf(sv), e2 = __expf(0.2f * sv);
    scanA[tid].x = e2;
    scanA[tid].y = e2 * hv;
    scanA[511 - tid].z = e1;
    scanA[511 - tid].w = e1 * hv;
  }
  __syncthreads();

  // Phase B6: inclusive Hillis-Steele float4 scan (9 steps).
  float4* srcb = scanA;
  float4* dstb = scanB;
  for (int d = 1; d < 512; d <<= 1) {
    float4 v = srcb[tid];
    if (tid >= d) {
      float4 u = srcb[tid - d];
      v.x += u.x; v.y += u.y; v.z += u.z; v.w += u.w;
    }
    dstb[tid] = v;
    __syncthreads();
    float4* t = srcb; srcb = dstb; dstb = t;
  }
  const float4* SC = srcb;

  // Phase B7: per destination: bucket lookup + boundary-exact combine.
  {
    const float theta = -d_own;
    int b = (int)fminf(fmaxf((theta - mn) * scale, 0.0f), 511.0f);
    unsigned k0 = b ? IS[b - 1] : 0u;   // elems in buckets < b: s < theta
    unsigned k1 = IS[b];                // elems in buckets <= b
    float F1 = __expf(d_own), F2 = __expf(0.2f * d_own);
    float P2 = 0.f, P2h = 0.f, S1 = 0.f, S1h = 0.f;
    if (k0 > 0)   { float4 t4 = SC[k0 - 1];   P2 = t4.x; P2h = t4.y; }
    if (k1 < 512) { float4 t4 = SC[511 - k1]; S1 = t4.z; S1h = t4.w; }
    float den = F1 * S1 + F2 * P2;
    float num = F1 * S1h + F2 * P2h;
    for (unsigned e = k0; e < k1; ++e) {  // boundary bucket: exact compare
      float se = sS[e], he = sH[e];
      float p = (se >= theta) ? F1 * __expf(se) : F2 * __expf(0.2f * se);
      den += p;
      num = fmaf(p, he, num);
    }
    if (CROSS) {  // self-loop: dst node's own source score
      float t = h_dst * a_src + d_own;
      float p = __expf(fmaxf(t, 0.2f * t));
      den += p;
      num = fmaf(p, h_dst, num);
    }
    float o = num / (den + 1e-16f) + bias;
    o = (o > 0.f) ? o : expm1f(o);  // ELU
    xt_out[hd * 1024 + D * 512 + tid] = o;
  }
}

// ----------------------------------------------------- final layer: mm2 ----
// grid 512 x 256: 2 rows x 128 cols per block.  h2 = x@W2, s2/d2 row dots.
__global__ __launch_bounds__(256) void mm2_kernel(
    const float* __restrict__ xt_in, const float* __restrict__ W2f,
    const float* __restrict__ vecs, float* __restrict__ h2,
    float* __restrict__ s2, float* __restrict__ d2) {
  __shared__ float rs[256], rd[256];
  const int tid = threadIdx.x;
  const int row = blockIdx.x * 2 + (tid >> 7);
  const int c = tid & 127;
  float acca = 0.f, accb = 0.f;
#pragma unroll 8
  for (int k = 0; k < 128; k += 2) {
    acca = fmaf(xt_in[k * 1024 + row], W2f[k * 128 + c], acca);
    accb = fmaf(xt_in[(k + 1) * 1024 + row], W2f[(k + 1) * 128 + c], accb);
  }
  float acc = acca + accb;
  h2[row * 128 + c] = acc;
  rs[tid] = acc * vecs[384 + c];  // a_src2
  rd[tid] = acc * vecs[512 + c];  // a_dst2
  __syncthreads();
  for (int off = 64; off > 0; off >>= 1) {
    if ((tid & 127) < off) { rs[tid] += rs[tid + off]; rd[tid] += rd[tid + off]; }
    __syncthreads();
  }
  if ((tid & 127) == 0) {
    s2[row] = rs[tid];
    d2[row] = rd[tid];
  }
}

// ---------------------------------------------------- final layer: attn ----
// Final conv: heads=1, ch=128, cross edges + self, no ELU, +b2.
__global__ __launch_bounds__(256) void att2_kernel(
    const float* __restrict__ h2, const float* __restrict__ s2,
    const float* __restrict__ d2, const float* __restrict__ vecs,
    void* __restrict__ out, const int* __restrict__ flag) {
  __shared__ __align__(16) float pT[512 * 4];  // pT[j*4 + ld]
  const int tid = threadIdx.x;
  const int dstBase = blockIdx.x * 4;
  const int srcBase = (dstBase < 512) ? 512 : 0;  // cross edges

  for (int e = tid; e < 2048; e += 256) {
    int j = e >> 2, ld = e & 3;
    float t = s2[srcBase + j] + d2[dstBase + ld];
    pT[e] = __expf(fmaxf(t, 0.2f * t));
  }
  __syncthreads();

  const int c = tid & 127;
  const int g = tid >> 7;            // 0 or 1 -> dst pair
  const int i0 = dstBase + 2 * g, i1 = i0 + 1;
  float den0 = 0.f, num0 = 0.f, den1 = 0.f, num1 = 0.f;
  const float* hrow = h2 + srcBase * 128 + c;
#pragma unroll 4
  for (int j = 0; j < 512; ++j) {
    float2 pv = *(const float2*)(pT + j * 4 + 2 * g);
    float hval = hrow[j * 128];
    den0 += pv.x; num0 = fmaf(pv.x, hval, num0);
    den1 += pv.y; num1 = fmaf(pv.y, hval, num1);
  }
  // self-loops
  float ts0 = s2[i0] + d2[i0];
  float ps0 = __expf(fmaxf(ts0, 0.2f * ts0));
  den0 += ps0; num0 = fmaf(ps0, h2[i0 * 128 + c], num0);
  float ts1 = s2[i1] + d2[i1];
  float ps1 = __expf(fmaxf(ts1, 0.2f * ts1));
  den1 += ps1; num1 = fmaf(ps1, h2[i1 * 128 + c], num1);

  float o0 = num0 / (den0 + 1e-16f) + vecs[640 + c];
  float o1 = num1 / (den1 + 1e-16f) + vecs[640 + c];
  if (*flag) {
    ((bf16*)out)[i0 * 128 + c] = __float2bfloat16(o0);
    ((bf16*)out)[i1 * 128 + c] = __float2bfloat16(o1);
  } else {
    ((float*)out)[i0 * 128 + c] = o0;
    ((float*)out)[i1 * 128 + c] = o1;
  }
}

// ------------------------------------------------------------- launcher ----
extern "C" void kernel_launch(void* const* d_in, const int* in_sizes, int n_in,
                              void* d_out, int out_size, void* d_ws, size_t ws_size,
                              hipStream_t stream) {
  (void)in_sizes; (void)n_in; (void)out_size; (void)ws_size;
  float* ws   = (float*)d_ws;
  float* xtA  = ws;            // 131072
  float* xtB  = ws + 131072;   // 131072
  float* h2   = ws + 262144;   // 131072
  float* W1f  = ws + 393216;   // 16384
  float* W2f  = ws + 409600;   // 16384
  float* vecs = ws + 425984;   // 768
  float* s2   = ws + 426752;   // 1024
  float* d2   = ws + 427776;   // 1024
  int*   flag = (int*)(ws + 428800);

  prep_kernel<<<64, 256, 0, stream>>>(d_in[0], d_in[1], d_in[2], d_in[3],
                                      d_in[4], d_in[5], d_in[6], d_in[7],
                                      d_in[8], d_in[9], xtA, W1f, W2f, vecs, flag);
  layer_kernel<0><<<256, 512, 0, stream>>>(xtA, xtB, W1f, vecs);  // L1 inside
  layer_kernel<1><<<256, 512, 0, stream>>>(xtB, xtA, W1f, vecs);  // L2 cross
  layer_kernel<0><<<256, 512, 0, stream>>>(xtA, xtB, W1f, vecs);  // L3 inside
  layer_kernel<1><<<256, 512, 0, stream>>>(xtB, xtA, W1f, vecs);  // L4 cross
  mm2_kernel<<<512, 256, 0, stream>>>(xtA, W2f, vecs, h2, s2, d2);
  att2_kernel<<<256, 256, 0, stream>>>(h2, s2, d2, vecs, d_out, flag);
}

// Round 10
// 202.869 us; speedup vs baseline: 2.8229x; 1.0165x over previous
//
#include <hip/hip_runtime.h>
#include <hip/hip_bf16.h>

// GAT on two 512-node cliques + bipartite cross edges, 5 GATConv layers.
// Dense-in-disguise edges: "inside" = clique within each set (+self),
// "cross" = full bipartite to opposite set (+self).
//
// R10: R9's separable-softmax + O(N) counting-sort layers (absmax 0), with
// the serial chain shortened: both 9-step LDS Hillis-Steele scans replaced
// by wave-shuffle scans (register-only, 6 steps, no barriers) + one LDS
// exchange of 8 wave totals.  Barriers/layer: ~25 -> 7.  The reversed
// float4 packing (8-way bank conflict on every scan step, SQ_LDS_BANK_
// CONFLICT=163k in R9) is replaced by direct prefix(e2)/suffix(e1) float2
// arrays.  prep/mm2/att2 verbatim R9.  7 dispatches.
// All internal f32; input/output dtype runtime-detected f32/bf16.

typedef __hip_bfloat16 bf16;

__device__ __forceinline__ float b2f(bf16 x) { return __bfloat162float(x); }

__device__ __forceinline__ int detect_bf16(const void* desc1) {
  const unsigned* u = (const unsigned*)desc1;
  int hits = 0;
#pragma unroll 8
  for (int i = 0; i < 256; ++i) {
    unsigned e = (u[i] >> 7) & 0xFFu;
    hits += (e >= 100u && e <= 140u) ? 1 : 0;
  }
  return hits >= 200 ? 1 : 0;
}

__device__ __forceinline__ float load_in(const void* p, int i, int bf) {
  return bf ? b2f(((const bf16*)p)[i]) : ((const float*)p)[i];
}

// ---------------------------------------------------------------- prep ----
__global__ __launch_bounds__(256) void prep_kernel(
    const void* __restrict__ desc1, const void* __restrict__ desc2,
    const void* __restrict__ W1,   const void* __restrict__ as1,
    const void* __restrict__ ad1,  const void* __restrict__ b1,
    const void* __restrict__ W2,   const void* __restrict__ as2,
    const void* __restrict__ ad2,  const void* __restrict__ b2,
    float* __restrict__ xt, float* __restrict__ W1f, float* __restrict__ W2f,
    float* __restrict__ vecs, int* __restrict__ flag) {
  const int bf = detect_bf16(desc1);
  if (blockIdx.x == 0 && threadIdx.x == 0) *flag = bf;
  const int total = 131072 + 16384 + 16384 + 6 * 128;
  for (int idx = blockIdx.x * blockDim.x + threadIdx.x; idx < total;
       idx += gridDim.x * blockDim.x) {
    if (idx < 131072) {
      int n = idx & 1023, c = idx >> 10;
      float v = (n < 512) ? load_in(desc1, n * 128 + c, bf)
                          : load_in(desc2, (n - 512) * 128 + c, bf);
      xt[idx] = v;  // xt[c*1024 + n]
    } else if (idx < 147456) {
      W1f[idx - 131072] = load_in(W1, idx - 131072, bf);
    } else if (idx < 163840) {
      W2f[idx - 147456] = load_in(W2, idx - 147456, bf);
    } else {
      int i = idx - 163840, o = i & 127;
      float v;
      if      (i < 128) v = load_in(as1, o, bf);
      else if (i < 256) v = load_in(ad1, o, bf);
      else if (i < 384) v = load_in(b1, o, bf);
      else if (i < 512) v = load_in(as2, o, bf);
      else if (i < 640) v = load_in(ad2, o, bf);
      else              v = load_in(b2, o, bf);
      vecs[i] = v;
    }
  }
}

// ------------------------------------------------------- fused GAT layer ----
// grid 256 = (S<<7)|hd, 512 threads.  Sources = set S; dst = S (inside) or
// 1-S (cross).  Thread tid owns src node S*512+tid AND dst node D*512+tid.
template <int CROSS>
__global__ __launch_bounds__(512) void layer_kernel(
    const float* __restrict__ xt_in, float* __restrict__ xt_out,
    const float* __restrict__ Wf, const float* __restrict__ vecs) {
  __shared__ float    sS[512];       // bucket-ordered s
  __shared__ float    sH[512];       // bucket-ordered h
  __shared__ unsigned hA[512];       // histogram
  __shared__ unsigned ISb[512];      // inclusive scan of hist
  __shared__ unsigned binNext[512];
  __shared__ float2   PRE[512];      // incl. prefix of (e2, e2*h), sorted ord
  __shared__ float2   SUF[512];      // incl. suffix of (e1, e1*h), sorted ord
  __shared__ float    red[16];
  __shared__ unsigned wTot[8];
  __shared__ float2   preTot[8];
  __shared__ float2   sufTot[8];

  const int tid  = threadIdx.x;
  const int lane = tid & 63;
  const int wave = tid >> 6;
  const int hd   = blockIdx.x & 127;
  const int S    = blockIdx.x >> 7;
  const int D    = CROSS ? (1 - S) : S;
  const float a_src = vecs[hd], a_dst = vecs[128 + hd], bias = vecs[256 + hd];

  // Phase A: h column for this head (src set; dst set too if cross).
  float accSa = 0.f, accSb = 0.f, accDa = 0.f, accDb = 0.f;
#pragma unroll 8
  for (int k = 0; k < 128; k += 2) {
    float w0 = Wf[k * 128 + hd];
    float w1 = Wf[(k + 1) * 128 + hd];
    accSa = fmaf(xt_in[k * 1024 + S * 512 + tid],       w0, accSa);
    accSb = fmaf(xt_in[(k + 1) * 1024 + S * 512 + tid], w1, accSb);
    if (CROSS) {
      accDa = fmaf(xt_in[k * 1024 + D * 512 + tid],       w0, accDa);
      accDb = fmaf(xt_in[(k + 1) * 1024 + D * 512 + tid], w1, accDb);
    }
  }
  const float h_src = accSa + accSb;
  const float h_dst = CROSS ? (accDa + accDb) : h_src;
  const float s_own = h_src * a_src;
  const float d_own = h_dst * a_dst;

  // B1: block min/max of s (wave shuffle + LDS combine); zero hist.
  {
    float mnw = s_own, mxw = s_own;
#pragma unroll
    for (int off = 32; off > 0; off >>= 1) {
      mnw = fminf(mnw, __shfl_down(mnw, off));
      mxw = fmaxf(mxw, __shfl_down(mxw, off));
    }
    if (lane == 0) { red[wave] = mnw; red[8 + wave] = mxw; }
  }
  hA[tid] = 0;
  binNext[tid] = 0;
  __syncthreads();                                        // (1)
  const float mn = fminf(fminf(fminf(red[0], red[1]), fminf(red[2], red[3])),
                         fminf(fminf(red[4], red[5]), fminf(red[6], red[7])));
  const float mx = fmaxf(fmaxf(fmaxf(red[8], red[9]), fmaxf(red[10], red[11])),
                         fmaxf(fmaxf(red[12], red[13]), fmaxf(red[14], red[15])));
  const float scale = 512.0f / fmaxf(mx - mn, 1e-20f);

  // B2: histogram (bin(x) monotone non-decreasing).
  const int myBin = (int)fminf(fmaxf((s_own - mn) * scale, 0.0f), 511.0f);
  atomicAdd(&hA[myBin], 1u);
  __syncthreads();                                        // (2)

  // B3: inclusive scan of hist via wave shuffles + wave-total exchange.
  {
    unsigned v = hA[tid];
#pragma unroll
    for (int off = 1; off < 64; off <<= 1) {
      unsigned u = __shfl_up(v, off);
      if (lane >= off) v += u;
    }
    if (lane == 63) wTot[wave] = v;
    __syncthreads();                                      // (3)
    unsigned pre = 0;
#pragma unroll
    for (int w = 0; w < 8; ++w) pre += (w < wave) ? wTot[w] : 0u;
    ISb[tid] = v + pre;
    __syncthreads();                                      // (4)
  }

  // B4: scatter into bucket-ordered arrays (order within bucket free).
  {
    unsigned base = myBin ? ISb[myBin - 1] : 0u;
    unsigned pos = base + atomicAdd(&binNext[myBin], 1u);
    sS[pos] = s_own;
    sH[pos] = h_src;
  }
  __syncthreads();                                        // (5)

  // B5: exps + prefix(e2,e2h) / suffix(e1,e1h) via wave shuffles.
  {
    const float sv = sS[tid];
    const float hv = sH[tid];
    const float e1 = __expf(sv), e2 = __expf(0.2f * sv);
    float p0 = e2, p1 = e2 * hv;     // prefix pair
    float q0 = e1, q1 = e1 * hv;     // suffix pair
#pragma unroll
    for (int off = 1; off < 64; off <<= 1) {
      float u0 = __shfl_up(p0, off), u1 = __shfl_up(p1, off);
      if (lane >= off) { p0 += u0; p1 += u1; }
      float v0 = __shfl_down(q0, off), v1 = __shfl_down(q1, off);
      if (lane + off < 64) { q0 += v0; q1 += v1; }
    }
    if (lane == 63) preTot[wave] = make_float2(p0, p1);
    if (lane == 0)  sufTot[wave] = make_float2(q0, q1);
    __syncthreads();                                      // (6)
    float a0 = 0.f, a1 = 0.f, b0 = 0.f, b1 = 0.f;
#pragma unroll
    for (int w = 0; w < 8; ++w) {
      float2 pt = preTot[w], st = sufTot[w];
      if (w < wave) { a0 += pt.x; a1 += pt.y; }
      if (w > wave) { b0 += st.x; b1 += st.y; }
    }
    PRE[tid] = make_float2(p0 + a0, p1 + a1);
    SUF[tid] = make_float2(q0 + b0, q1 + b1);
    __syncthreads();                                      // (7)
  }

  // B7: per destination: bucket lookup + boundary-exact combine.
  {
    const float theta = -d_own;
    int b = (int)fminf(fmaxf((theta - mn) * scale, 0.0f), 511.0f);
    unsigned k0 = b ? ISb[b - 1] : 0u;  // elems in buckets < b: s < theta
    unsigned k1 = ISb[b];               // elems in buckets <= b
    float F1 = __expf(d_own), F2 = __expf(0.2f * d_own);
    float P2 = 0.f, P2h = 0.f, S1 = 0.f, S1h = 0.f;
    if (k0 > 0)   { float2 t2 = PRE[k0 - 1]; P2 = t2.x; P2h = t2.y; }
    if (k1 < 512) { float2 t2 = SUF[k1];     S1 = t2.x; S1h = t2.y; }
    float den = F1 * S1 + F2 * P2;
    float num = F1 * S1h + F2 * P2h;
    for (unsigned e = k0; e < k1; ++e) {  // boundary bucket: exact compare
      float se = sS[e], he = sH[e];
      float p = (se >= theta) ? F1 * __expf(se) : F2 * __expf(0.2f * se);
      den += p;
      num = fmaf(p, he, num);
    }
    if (CROSS) {  // self-loop: dst node's own source score
      float t = h_dst * a_src + d_own;
      float p = __expf(fmaxf(t, 0.2f * t));
      den += p;
      num = fmaf(p, h_dst, num);
    }
    float o = num / (den + 1e-16f) + bias;
    o = (o > 0.f) ? o : expm1f(o);  // ELU
    xt_out[hd * 1024 + D * 512 + tid] = o;
  }
}

// ----------------------------------------------------- final layer: mm2 ----
// grid 512 x 256: 2 rows x 128 cols per block.  h2 = x@W2, s2/d2 row dots.
__global__ __launch_bounds__(256) void mm2_kernel(
    const float* __restrict__ xt_in, const float* __restrict__ W2f,
    const float* __restrict__ vecs, float* __restrict__ h2,
    float* __restrict__ s2, float* __restrict__ d2) {
  __shared__ float rs[256], rd[256];
  const int tid = threadIdx.x;
  const int row = blockIdx.x * 2 + (tid >> 7);
  const int c = tid & 127;
  float acca = 0.f, accb = 0.f;
#pragma unroll 8
  for (int k = 0; k < 128; k += 2) {
    acca = fmaf(xt_in[k * 1024 + row], W2f[k * 128 + c], acca);
    accb = fmaf(xt_in[(k + 1) * 1024 + row], W2f[(k + 1) * 128 + c], accb);
  }
  float acc = acca + accb;
  h2[row * 128 + c] = acc;
  rs[tid] = acc * vecs[384 + c];  // a_src2
  rd[tid] = acc * vecs[512 + c];  // a_dst2
  __syncthreads();
  for (int off = 64; off > 0; off >>= 1) {
    if ((tid & 127) < off) { rs[tid] += rs[tid + off]; rd[tid] += rd[tid + off]; }
    __syncthreads();
  }
  if ((tid & 127) == 0) {
    s2[row] = rs[tid];
    d2[row] = rd[tid];
  }
}

// ---------------------------------------------------- final layer: attn ----
// Final conv: heads=1, ch=128, cross edges + self, no ELU, +b2.
__global__ __launch_bounds__(256) void att2_kernel(
    const float* __restrict__ h2, const float* __restrict__ s2,
    const float* __restrict__ d2, const float* __restrict__ vecs,
    void* __restrict__ out, const int* __restrict__ flag) {
  __shared__ __align__(16) float pT[512 * 4];  // pT[j*4 + ld]
  const int tid = threadIdx.x;
  const int dstBase = blockIdx.x * 4;
  const int srcBase = (dstBase < 512) ? 512 : 0;  // cross edges

  for (int e = tid; e < 2048; e += 256) {
    int j = e >> 2, ld = e & 3;
    float t = s2[srcBase + j] + d2[dstBase + ld];
    pT[e] = __expf(fmaxf(t, 0.2f * t));
  }
  __syncthreads();

  const int c = tid & 127;
  const int g = tid >> 7;            // 0 or 1 -> dst pair
  const int i0 = dstBase + 2 * g, i1 = i0 + 1;
  float den0 = 0.f, num0 = 0.f, den1 = 0.f, num1 = 0.f;
  const float* hrow = h2 + srcBase * 128 + c;
#pragma unroll 4
  for (int j = 0; j < 512; ++j) {
    float2 pv = *(const float2*)(pT + j * 4 + 2 * g);
    float hval = hrow[j * 128];
    den0 += pv.x; num0 = fmaf(pv.x, hval, num0);
    den1 += pv.y; num1 = fmaf(pv.y, hval, num1);
  }
  // self-loops
  float ts0 = s2[i0] + d2[i0];
  float ps0 = __expf(fmaxf(ts0, 0.2f * ts0));
  den0 += ps0; num0 = fmaf(ps0, h2[i0 * 128 + c], num0);
  float ts1 = s2[i1] + d2[i1];
  float ps1 = __expf(fmaxf(ts1, 0.2f * ts1));
  den1 += ps1; num1 = fmaf(ps1, h2[i1 * 128 + c], num1);

  float o0 = num0 / (den0 + 1e-16f) + vecs[640 + c];
  float o1 = num1 / (den1 + 1e-16f) + vecs[640 + c];
  if (*flag) {
    ((bf16*)out)[i0 * 128 + c] = __float2bfloat16(o0);
    ((bf16*)out)[i1 * 128 + c] = __float2bfloat16(o1);
  } else {
    ((float*)out)[i0 * 128 + c] = o0;
    ((float*)out)[i1 * 128 + c] = o1;
  }
}

// ------------------------------------------------------------- launcher ----
extern "C" void kernel_launch(void* const* d_in, const int* in_sizes, int n_in,
                              void* d_out, int out_size, void* d_ws, size_t ws_size,
                              hipStream_t stream) {
  (void)in_sizes; (void)n_in; (void)out_size; (void)ws_size;
  float* ws   = (float*)d_ws;
  float* xtA  = ws;            // 131072
  float* xtB  = ws + 131072;   // 131072
  float* h2   = ws + 262144;   // 131072
  float* W1f  = ws + 393216;   // 16384
  float* W2f  = ws + 409600;   // 16384
  float* vecs = ws + 425984;   // 768
  float* s2   = ws + 426752;   // 1024
  float* d2   = ws + 427776;   // 1024
  int*   flag = (int*)(ws + 428800);

  prep_kernel<<<64, 256, 0, stream>>>(d_in[0], d_in[1], d_in[2], d_in[3],
                                      d_in[4], d_in[5], d_in[6], d_in[7],
                                      d_in[8], d_in[9], xtA, W1f, W2f, vecs, flag);
  layer_kernel<0><<<256, 512, 0, stream>>>(xtA, xtB, W1f, vecs);  // L1 inside
  layer_kernel<1><<<256, 512, 0, stream>>>(xtB, xtA, W1f, vecs);  // L2 cross
  layer_kernel<0><<<256, 512, 0, stream>>>(xtA, xtB, W1f, vecs);  // L3 inside
  layer_kernel<1><<<256, 512, 0, stream>>>(xtB, xtA, W1f, vecs);  // L4 cross
  mm2_kernel<<<512, 256, 0, stream>>>(xtA, W2f, vecs, h2, s2, d2);
  att2_kernel<<<256, 256, 0, stream>>>(h2, s2, d2, vecs, d_out, flag);
}

// Round 11
// 180.031 us; speedup vs baseline: 3.1810x; 1.1269x over previous
//
#include <hip/hip_runtime.h>
#include <hip/hip_bf16.h>

// GAT on two 512-node cliques + bipartite cross edges, 5 GATConv layers.
// Dense-in-disguise edges: "inside" = clique within each set (+self),
// "cross" = full bipartite to opposite set (+self).
//
// R11: R10's separable-softmax + counting-sort layers (absmax 0) with the
// REAL bottleneck fixed: VGPR_Count=28 showed the compiler was issuing
// phase-A's 256-512 per-thread global loads in tiny batches (few
// outstanding loads -> serial L2/LLC latency, VALUBusy 9.5%, occ 6.7%).
// Fix: explicit 16-deep load buffers (16-32 loads in flight) +
// __launch_bounds__(512,2) to raise the VGPR cap; same batching in
// mm2 (16-deep) and att2 (8-deep strided h2 reads).
// All internal f32; input/output dtype runtime-detected f32/bf16.

typedef __hip_bfloat16 bf16;

__device__ __forceinline__ float b2f(bf16 x) { return __bfloat162float(x); }

__device__ __forceinline__ int detect_bf16(const void* desc1) {
  const unsigned* u = (const unsigned*)desc1;
  int hits = 0;
#pragma unroll 8
  for (int i = 0; i < 256; ++i) {
    unsigned e = (u[i] >> 7) & 0xFFu;
    hits += (e >= 100u && e <= 140u) ? 1 : 0;
  }
  return hits >= 200 ? 1 : 0;
}

__device__ __forceinline__ float load_in(const void* p, int i, int bf) {
  return bf ? b2f(((const bf16*)p)[i]) : ((const float*)p)[i];
}

// ---------------------------------------------------------------- prep ----
__global__ __launch_bounds__(256) void prep_kernel(
    const void* __restrict__ desc1, const void* __restrict__ desc2,
    const void* __restrict__ W1,   const void* __restrict__ as1,
    const void* __restrict__ ad1,  const void* __restrict__ b1,
    const void* __restrict__ W2,   const void* __restrict__ as2,
    const void* __restrict__ ad2,  const void* __restrict__ b2,
    float* __restrict__ xt, float* __restrict__ W1f, float* __restrict__ W2f,
    float* __restrict__ vecs, int* __restrict__ flag) {
  const int bf = detect_bf16(desc1);
  if (blockIdx.x == 0 && threadIdx.x == 0) *flag = bf;
  const int total = 131072 + 16384 + 16384 + 6 * 128;
  for (int idx = blockIdx.x * blockDim.x + threadIdx.x; idx < total;
       idx += gridDim.x * blockDim.x) {
    if (idx < 131072) {
      int n = idx & 1023, c = idx >> 10;
      float v = (n < 512) ? load_in(desc1, n * 128 + c, bf)
                          : load_in(desc2, (n - 512) * 128 + c, bf);
      xt[idx] = v;  // xt[c*1024 + n]
    } else if (idx < 147456) {
      W1f[idx - 131072] = load_in(W1, idx - 131072, bf);
    } else if (idx < 163840) {
      W2f[idx - 147456] = load_in(W2, idx - 147456, bf);
    } else {
      int i = idx - 163840, o = i & 127;
      float v;
      if      (i < 128) v = load_in(as1, o, bf);
      else if (i < 256) v = load_in(ad1, o, bf);
      else if (i < 384) v = load_in(b1, o, bf);
      else if (i < 512) v = load_in(as2, o, bf);
      else if (i < 640) v = load_in(ad2, o, bf);
      else              v = load_in(b2, o, bf);
      vecs[i] = v;
    }
  }
}

// ------------------------------------------------------- fused GAT layer ----
// grid 256 = (S<<7)|hd, 512 threads.  Sources = set S; dst = S (inside) or
// 1-S (cross).  Thread tid owns src node S*512+tid AND dst node D*512+tid.
template <int CROSS>
__global__ __launch_bounds__(512, 2) void layer_kernel(
    const float* __restrict__ xt_in, float* __restrict__ xt_out,
    const float* __restrict__ Wf, const float* __restrict__ vecs) {
  __shared__ float    sS[512];       // bucket-ordered s
  __shared__ float    sH[512];       // bucket-ordered h
  __shared__ unsigned hA[512];       // histogram
  __shared__ unsigned ISb[512];      // inclusive scan of hist
  __shared__ unsigned binNext[512];
  __shared__ float2   PRE[512];      // incl. prefix of (e2, e2*h), sorted ord
  __shared__ float2   SUF[512];      // incl. suffix of (e1, e1*h), sorted ord
  __shared__ float    red[16];
  __shared__ unsigned wTot[8];
  __shared__ float2   preTot[8];
  __shared__ float2   sufTot[8];

  const int tid  = threadIdx.x;
  const int lane = tid & 63;
  const int wave = tid >> 6;
  const int hd   = blockIdx.x & 127;
  const int S    = blockIdx.x >> 7;
  const int D    = CROSS ? (1 - S) : S;
  const float a_src = vecs[hd], a_dst = vecs[128 + hd], bias = vecs[256 + hd];

  // Phase A: h column for this head.  16-deep explicit load batches so the
  // compiler keeps 16 (inside) / 32 (cross) loads in flight per group.
  float accS0 = 0.f, accS1 = 0.f, accD0 = 0.f, accD1 = 0.f;
  {
    const float* baseS = xt_in + S * 512 + tid;
    const float* baseD = xt_in + D * 512 + tid;
    for (int kk = 0; kk < 128; kk += 16) {
      float xs[16], xd[16];
#pragma unroll
      for (int u = 0; u < 16; ++u) {
        xs[u] = baseS[(kk + u) * 1024];
        if (CROSS) xd[u] = baseD[(kk + u) * 1024];
      }
#pragma unroll
      for (int u = 0; u < 16; u += 2) {
        float w0 = Wf[(kk + u) * 128 + hd];
        float w1 = Wf[(kk + u + 1) * 128 + hd];
        accS0 = fmaf(xs[u],     w0, accS0);
        accS1 = fmaf(xs[u + 1], w1, accS1);
        if (CROSS) {
          accD0 = fmaf(xd[u],     w0, accD0);
          accD1 = fmaf(xd[u + 1], w1, accD1);
        }
      }
    }
  }
  const float h_src = accS0 + accS1;
  const float h_dst = CROSS ? (accD0 + accD1) : h_src;
  const float s_own = h_src * a_src;
  const float d_own = h_dst * a_dst;

  // B1: block min/max of s (wave shuffle + LDS combine); zero hist.
  {
    float mnw = s_own, mxw = s_own;
#pragma unroll
    for (int off = 32; off > 0; off >>= 1) {
      mnw = fminf(mnw, __shfl_down(mnw, off));
      mxw = fmaxf(mxw, __shfl_down(mxw, off));
    }
    if (lane == 0) { red[wave] = mnw; red[8 + wave] = mxw; }
  }
  hA[tid] = 0;
  binNext[tid] = 0;
  __syncthreads();                                        // (1)
  const float mn = fminf(fminf(fminf(red[0], red[1]), fminf(red[2], red[3])),
                         fminf(fminf(red[4], red[5]), fminf(red[6], red[7])));
  const float mx = fmaxf(fmaxf(fmaxf(red[8], red[9]), fmaxf(red[10], red[11])),
                         fmaxf(fmaxf(red[12], red[13]), fmaxf(red[14], red[15])));
  const float scale = 512.0f / fmaxf(mx - mn, 1e-20f);

  // B2: histogram (bin(x) monotone non-decreasing).
  const int myBin = (int)fminf(fmaxf((s_own - mn) * scale, 0.0f), 511.0f);
  atomicAdd(&hA[myBin], 1u);
  __syncthreads();                                        // (2)

  // B3: inclusive scan of hist via wave shuffles + wave-total exchange.
  {
    unsigned v = hA[tid];
#pragma unroll
    for (int off = 1; off < 64; off <<= 1) {
      unsigned u = __shfl_up(v, off);
      if (lane >= off) v += u;
    }
    if (lane == 63) wTot[wave] = v;
    __syncthreads();                                      // (3)
    unsigned pre = 0;
#pragma unroll
    for (int w = 0; w < 8; ++w) pre += (w < wave) ? wTot[w] : 0u;
    ISb[tid] = v + pre;
    __syncthreads();                                      // (4)
  }

  // B4: scatter into bucket-ordered arrays (order within bucket free).
  {
    unsigned base = myBin ? ISb[myBin - 1] : 0u;
    unsigned pos = base + atomicAdd(&binNext[myBin], 1u);
    sS[pos] = s_own;
    sH[pos] = h_src;
  }
  __syncthreads();                                        // (5)

  // B5: exps + prefix(e2,e2h) / suffix(e1,e1h) via wave shuffles.
  {
    const float sv = sS[tid];
    const float hv = sH[tid];
    const float e1 = __expf(sv), e2 = __expf(0.2f * sv);
    float p0 = e2, p1 = e2 * hv;     // prefix pair
    float q0 = e1, q1 = e1 * hv;     // suffix pair
#pragma unroll
    for (int off = 1; off < 64; off <<= 1) {
      float u0 = __shfl_up(p0, off), u1 = __shfl_up(p1, off);
      if (lane >= off) { p0 += u0; p1 += u1; }
      float v0 = __shfl_down(q0, off), v1 = __shfl_down(q1, off);
      if (lane + off < 64) { q0 += v0; q1 += v1; }
    }
    if (lane == 63) preTot[wave] = make_float2(p0, p1);
    if (lane == 0)  sufTot[wave] = make_float2(q0, q1);
    __syncthreads();                                      // (6)
    float a0 = 0.f, a1 = 0.f, b0 = 0.f, b1 = 0.f;
#pragma unroll
    for (int w = 0; w < 8; ++w) {
      float2 pt = preTot[w], st = sufTot[w];
      if (w < wave) { a0 += pt.x; a1 += pt.y; }
      if (w > wave) { b0 += st.x; b1 += st.y; }
    }
    PRE[tid] = make_float2(p0 + a0, p1 + a1);
    SUF[tid] = make_float2(q0 + b0, q1 + b1);
    __syncthreads();                                      // (7)
  }

  // B7: per destination: bucket lookup + boundary-exact combine.
  {
    const float theta = -d_own;
    int b = (int)fminf(fmaxf((theta - mn) * scale, 0.0f), 511.0f);
    unsigned k0 = b ? ISb[b - 1] : 0u;  // elems in buckets < b: s < theta
    unsigned k1 = ISb[b];               // elems in buckets <= b
    float F1 = __expf(d_own), F2 = __expf(0.2f * d_own);
    float P2 = 0.f, P2h = 0.f, S1 = 0.f, S1h = 0.f;
    if (k0 > 0)   { float2 t2 = PRE[k0 - 1]; P2 = t2.x; P2h = t2.y; }
    if (k1 < 512) { float2 t2 = SUF[k1];     S1 = t2.x; S1h = t2.y; }
    float den = F1 * S1 + F2 * P2;
    float num = F1 * S1h + F2 * P2h;
    for (unsigned e = k0; e < k1; ++e) {  // boundary bucket: exact compare
      float se = sS[e], he = sH[e];
      float p = (se >= theta) ? F1 * __expf(se) : F2 * __expf(0.2f * se);
      den += p;
      num = fmaf(p, he, num);
    }
    if (CROSS) {  // self-loop: dst node's own source score
      float t = h_dst * a_src + d_own;
      float p = __expf(fmaxf(t, 0.2f * t));
      den += p;
      num = fmaf(p, h_dst, num);
    }
    float o = num / (den + 1e-16f) + bias;
    o = (o > 0.f) ? o : expm1f(o);  // ELU
    xt_out[hd * 1024 + D * 512 + tid] = o;
  }
}

// ----------------------------------------------------- final layer: mm2 ----
// grid 512 x 256: 2 rows x 128 cols per block.  h2 = x@W2, s2/d2 row dots.
__global__ __launch_bounds__(256, 2) void mm2_kernel(
    const float* __restrict__ xt_in, const float* __restrict__ W2f,
    const float* __restrict__ vecs, float* __restrict__ h2,
    float* __restrict__ s2, float* __restrict__ d2) {
  __shared__ float rs[256], rd[256];
  const int tid = threadIdx.x;
  const int row = blockIdx.x * 2 + (tid >> 7);
  const int c = tid & 127;
  float acc0 = 0.f, acc1 = 0.f;
  for (int kk = 0; kk < 128; kk += 16) {
    float xb[16];
#pragma unroll
    for (int u = 0; u < 16; ++u) xb[u] = xt_in[(kk + u) * 1024 + row];
#pragma unroll
    for (int u = 0; u < 16; u += 2) {
      acc0 = fmaf(xb[u],     W2f[(kk + u) * 128 + c],     acc0);
      acc1 = fmaf(xb[u + 1], W2f[(kk + u + 1) * 128 + c], acc1);
    }
  }
  float acc = acc0 + acc1;
  h2[row * 128 + c] = acc;
  rs[tid] = acc * vecs[384 + c];  // a_src2
  rd[tid] = acc * vecs[512 + c];  // a_dst2
  __syncthreads();
  for (int off = 64; off > 0; off >>= 1) {
    if ((tid & 127) < off) { rs[tid] += rs[tid + off]; rd[tid] += rd[tid + off]; }
    __syncthreads();
  }
  if ((tid & 127) == 0) {
    s2[row] = rs[tid];
    d2[row] = rd[tid];
  }
}

// ---------------------------------------------------- final layer: attn ----
// Final conv: heads=1, ch=128, cross edges + self, no ELU, +b2.
__global__ __launch_bounds__(256, 1) void att2_kernel(
    const float* __restrict__ h2, const float* __restrict__ s2,
    const float* __restrict__ d2, const float* __restrict__ vecs,
    void* __restrict__ out, const int* __restrict__ flag) {
  __shared__ __align__(16) float pT[512 * 4];  // pT[j*4 + ld]
  const int tid = threadIdx.x;
  const int dstBase = blockIdx.x * 4;
  const int srcBase = (dstBase < 512) ? 512 : 0;  // cross edges

  for (int e = tid; e < 2048; e += 256) {
    int j = e >> 2, ld = e & 3;
    float t = s2[srcBase + j] + d2[dstBase + ld];
    pT[e] = __expf(fmaxf(t, 0.2f * t));
  }
  __syncthreads();

  const int c = tid & 127;
  const int g = tid >> 7;            // 0 or 1 -> dst pair
  const int i0 = dstBase + 2 * g, i1 = i0 + 1;
  float den0 = 0.f, num0 = 0.f, den1 = 0.f, num1 = 0.f;
  const float* hrow = h2 + srcBase * 128 + c;
  for (int j0 = 0; j0 < 512; j0 += 8) {
    float hb[8];
#pragma unroll
    for (int u = 0; u < 8; ++u) hb[u] = hrow[(j0 + u) * 128];
#pragma unroll
    for (int u = 0; u < 8; ++u) {
      float2 pv = *(const float2*)(pT + (j0 + u) * 4 + 2 * g);
      den0 += pv.x; num0 = fmaf(pv.x, hb[u], num0);
      den1 += pv.y; num1 = fmaf(pv.y, hb[u], num1);
    }
  }
  // self-loops
  float ts0 = s2[i0] + d2[i0];
  float ps0 = __expf(fmaxf(ts0, 0.2f * ts0));
  den0 += ps0; num0 = fmaf(ps0, h2[i0 * 128 + c], num0);
  float ts1 = s2[i1] + d2[i1];
  float ps1 = __expf(fmaxf(ts1, 0.2f * ts1));
  den1 += ps1; num1 = fmaf(ps1, h2[i1 * 128 + c], num1);

  float o0 = num0 / (den0 + 1e-16f) + vecs[640 + c];
  float o1 = num1 / (den1 + 1e-16f) + vecs[640 + c];
  if (*flag) {
    ((bf16*)out)[i0 * 128 + c] = __float2bfloat16(o0);
    ((bf16*)out)[i1 * 128 + c] = __float2bfloat16(o1);
  } else {
    ((float*)out)[i0 * 128 + c] = o0;
    ((float*)out)[i1 * 128 + c] = o1;
  }
}

// ------------------------------------------------------------- launcher ----
extern "C" void kernel_launch(void* const* d_in, const int* in_sizes, int n_in,
                              void* d_out, int out_size, void* d_ws, size_t ws_size,
                              hipStream_t stream) {
  (void)in_sizes; (void)n_in; (void)out_size; (void)ws_size;
  float* ws   = (float*)d_ws;
  float* xtA  = ws;            // 131072
  float* xtB  = ws + 131072;   // 131072
  float* h2   = ws + 262144;   // 131072
  float* W1f  = ws + 393216;   // 16384
  float* W2f  = ws + 409600;   // 16384
  float* vecs = ws + 425984;   // 768
  float* s2   = ws + 426752;   // 1024
  float* d2   = ws + 427776;   // 1024
  int*   flag = (int*)(ws + 428800);

  prep_kernel<<<64, 256, 0, stream>>>(d_in[0], d_in[1], d_in[2], d_in[3],
                                      d_in[4], d_in[5], d_in[6], d_in[7],
                                      d_in[8], d_in[9], xtA, W1f, W2f, vecs, flag);
  layer_kernel<0><<<256, 512, 0, stream>>>(xtA, xtB, W1f, vecs);  // L1 inside
  layer_kernel<1><<<256, 512, 0, stream>>>(xtB, xtA, W1f, vecs);  // L2 cross
  layer_kernel<0><<<256, 512, 0, stream>>>(xtA, xtB, W1f, vecs);  // L3 inside
  layer_kernel<1><<<256, 512, 0, stream>>>(xtB, xtA, W1f, vecs);  // L4 cross
  mm2_kernel<<<512, 256, 0, stream>>>(xtA, W2f, vecs, h2, s2, d2);
  att2_kernel<<<256, 256, 0, stream>>>(h2, s2, d2, vecs, d_out, flag);
}